// Round 8
// baseline (518.346 us; speedup 1.0000x reference)
//
#include <hip/hip_runtime.h>
#include <hip/hip_bf16.h>

#define EPS 1e-5f
#define INV_VRF 4.4194173824159220e-02f  // 2/sqrt(2048)

#define NB 32
#define NP 2048
#define NI 4096
#define ND 64
#define NL 256

#define ATTN_OFF 32L
#define OUT_OFF  268435488L  // 32 + 32*2048*4096
#define LSTRIDE 2056         // bf16 elems; 4112B rows: 16B-aligned, banks spread by 4/row

typedef __attribute__((ext_vector_type(4))) float vf4;
typedef __attribute__((ext_vector_type(8))) short vs8;

__device__ __forceinline__ unsigned short f2bf(float f) {
  unsigned int u = __float_as_uint(f);
  unsigned int r = (u + 0x7FFFu + ((u >> 16) & 1u)) >> 16;
  return (unsigned short)r;
}

__device__ __forceinline__ float bf2f(unsigned short s) {
  unsigned int u = ((unsigned int)s) << 16;
  return __uint_as_float(u);
}

// permute k-index d (0..63) into MFMA-fragment element order, so a frag for
// (kk, g) is the contiguous 16B at element [kk*32 + g*8 .. +8).
__device__ __forceinline__ int kperm(int d) {
  int dd = d & 31;
  return (d & 32) + (((dd & 15) >> 2) << 3) + ((dd >> 4) << 2) + (dd & 3);
}

// ---------------- K1: qm = lrelu( lrelu(LN(s*qw)) @ qw2 ), bf16 (permuted cols) ----------------
__global__ __launch_bounds__(256) void k_qm(
    const float* __restrict__ pathway, const float* __restrict__ qw,
    const float* __restrict__ qw2, const float* __restrict__ q_g,
    const float* __restrict__ q_b, unsigned short* __restrict__ qm)
{
  __shared__ float qw2s[64 * 64];
  int tid = threadIdx.x, lane = tid & 63, w = tid >> 6;
  for (int idx = tid; idx < 4096; idx += 256) qw2s[idx] = qw2[idx];
  float qwv = qw[lane], qg = q_g[lane], qb = q_b[lane];
  float s1 = qwv, s2 = qwv * qwv;
  #pragma unroll
  for (int m = 32; m; m >>= 1) { s1 += __shfl_xor(s1, m); s2 += __shfl_xor(s2, m); }
  float mq = s1 * (1.f / 64.f), vq = s2 * (1.f / 64.f) - mq * mq;
  float qc = qwv - mq;
  int pdst = kperm(lane);
  __syncthreads();
  long base = (long)blockIdx.x * 32 + w * 8;
  for (int r = 0; r < 8; ++r) {
    long row = base + r;
    float s = pathway[row];
    float alpha = s * rsqrtf(s * s * vq + EPS);
    float t = alpha * qc * qg + qb;
    t = t >= 0.f ? t : 0.2f * t;
    float acc = 0.f;
    #pragma unroll
    for (int h = 0; h < 64; ++h) acc += __shfl(t, h) * qw2s[h * 64 + lane];
    acc = acc >= 0.f ? acc : 0.2f * acc;
    qm[row * 64 + pdst] = f2bf(acc);
  }
}

// ---------------- K2: km = LN(img_t@kw) bf16 (permuted cols) ; vm = lrelu(LN(img_t@vw))@vw2 ----------------
__global__ __launch_bounds__(256) void k_kmvm(
    const float* __restrict__ img, const float* __restrict__ kw,
    const float* __restrict__ vw, const float* __restrict__ vw2,
    const float* __restrict__ k_g, const float* __restrict__ k_b,
    const float* __restrict__ v_g, const float* __restrict__ v_b,
    unsigned short* __restrict__ km, float* __restrict__ vm)
{
  int tid = threadIdx.x, lane = tid & 63, w = tid >> 6;
  long row = (long)blockIdx.x * 4 + w;      // b*4096 + i
  int b = (int)(row >> 12), i = (int)(row & 4095);
  const float* ib = img + (long)b * 4 * 4096 + i;
  float xv = (lane < 4) ? ib[lane * 4096] : 0.f;
  float x0 = __shfl(xv, 0), x1 = __shfl(xv, 1), x2 = __shfl(xv, 2), x3 = __shfl(xv, 3);
  int d = lane;
  float kp = x0 * kw[d] + x1 * kw[64 + d] + x2 * kw[128 + d] + x3 * kw[192 + d];
  float vp = x0 * vw[d] + x1 * vw[64 + d] + x2 * vw[128 + d] + x3 * vw[192 + d];
  float a1 = kp, a2 = kp * kp, a3 = vp, a4 = vp * vp;
  #pragma unroll
  for (int m = 32; m; m >>= 1) {
    a1 += __shfl_xor(a1, m); a2 += __shfl_xor(a2, m);
    a3 += __shfl_xor(a3, m); a4 += __shfl_xor(a4, m);
  }
  float mk = a1 * (1.f / 64.f), vk = a2 * (1.f / 64.f) - mk * mk;
  float mv = a3 * (1.f / 64.f), vv = a4 * (1.f / 64.f) - mv * mv;
  float kmv = (kp - mk) * rsqrtf(vk + EPS) * k_g[d] + k_b[d];
  km[row * 64 + kperm(d)] = f2bf(kmv);
  float y = (vp - mv) * rsqrtf(vv + EPS) * v_g[d] + v_b[d];
  y = y >= 0.f ? y : 0.2f * y;
  float pv = y * vw2[d];
  #pragma unroll
  for (int m = 32; m; m >>= 1) pv += __shfl_xor(pv, m);
  if (lane == 0) vm[row] = pv;
}

// ---------------- K3: attn = softsign(relu(qm@km^T)/vrf) -> d_out ; out-partials -> ws ----------------
// Phase-split: compute 16x2048 tile to LDS (bf16, NO global stores), barrier, then a
// pure store sweep (per wave 4 rows x 8KB sequential NT stores, NO loads -> no vmcnt drains).
// 2 blocks/CU overlap: one block's store phase runs under the other's compute phase.
__global__ __launch_bounds__(256) void k_attn(
    const unsigned short* __restrict__ qm, const unsigned short* __restrict__ km,
    const float* __restrict__ vm, float* __restrict__ part, float* __restrict__ dout)
{
  __shared__ __align__(16) unsigned short att_s[16 * LSTRIDE];  // 65792 B
  __shared__ float red2[4][16];
  int tid = threadIdx.x, lane = tid & 63, w = tid >> 6;
  int g = lane >> 4, c = lane & 15;
  // XCD swizzle: 8192 blocks -> 1024 per XCD, blocks of one b stay on one XCD
  int bid = blockIdx.x;
  int lbid = (bid & 7) * 1024 + (bid >> 3);
  int b = lbid >> 8, rest = lbid & 255;
  int ptile = rest >> 1, half = rest & 1;
  long p_base = (long)b * NP + ptile * 16;

  // A fragments: block's 16 rows, permuted element order
  const unsigned short* qrow = qm + (p_base + c) * 64;
  vs8 afr0 = *(const vs8*)(qrow + g * 8);
  vs8 afr1 = *(const vs8*)(qrow + 32 + g * 8);

  const unsigned short* kb = km + (long)b * NI * 64;
  const float* vmb = vm + (long)b * NI;
  float oacc[4] = {0.f, 0.f, 0.f, 0.f};

  // ---- compute phase: wave w covers cols [w*512, w*512+512) of this half ----
  #pragma unroll
  for (int s4 = 0; s4 < 4; ++s4) {
    int col0 = w * 512 + s4 * 128;
    int i0 = half * 2048 + col0;
    vf4 acc[8];
    #pragma unroll
    for (int nt = 0; nt < 8; ++nt) acc[nt] = (vf4){0.f, 0.f, 0.f, 0.f};
    #pragma unroll
    for (int nt = 0; nt < 8; ++nt) {
      const unsigned short* krow = kb + (long)(i0 + nt * 16 + c) * 64;
      vs8 b0 = *(const vs8*)(krow + g * 8);
      vs8 b1 = *(const vs8*)(krow + 32 + g * 8);
      acc[nt] = __builtin_amdgcn_mfma_f32_16x16x32_bf16(afr0, b0, acc[nt], 0, 0, 0);
      acc[nt] = __builtin_amdgcn_mfma_f32_16x16x32_bf16(afr1, b1, acc[nt], 0, 0, 0);
    }
    #pragma unroll
    for (int nt = 0; nt < 8; ++nt) {
      float vmv = vmb[i0 + nt * 16 + c];
      #pragma unroll
      for (int r = 0; r < 4; ++r) {
        float x = fmaxf(acc[nt][r], 0.f) * INV_VRF;
        float y = x * __builtin_amdgcn_rcpf(x + 0.5f);
        int row = g * 4 + r;
        att_s[row * LSTRIDE + col0 + nt * 16 + c] = f2bf(y);
        oacc[r] += y * vmv;
      }
    }
  }
  // out-partials: reduce over c-lanes, then across waves via LDS
  #pragma unroll
  for (int m = 1; m <= 8; m <<= 1) {
    #pragma unroll
    for (int r = 0; r < 4; ++r) oacc[r] += __shfl_xor(oacc[r], m);
  }
  if (c == 0) {
    #pragma unroll
    for (int r = 0; r < 4; ++r) red2[w][g * 4 + r] = oacc[r];
  }
  __syncthreads();
  if (tid < 16)
    part[(long)half * 65536 + p_base + tid] =
        red2[0][tid] + red2[1][tid] + red2[2][tid] + red2[3][tid];

  // ---- store phase: wave w stores rows w*4..w*4+3, 8KB sequential each, no loads ----
  #pragma unroll
  for (int r = 0; r < 4; ++r) {
    int row = w * 4 + r;
    const unsigned short* lsrc = att_s + row * LSTRIDE;
    float* gdst = dout + ATTN_OFF + (p_base + row) * (long)NI + half * 2048;
    #pragma unroll
    for (int ck = 0; ck < 4; ++ck) {
      vs8 v = *(const vs8*)(lsrc + ck * 512 + lane * 8);
      vf4 lo, hi;
      #pragma unroll
      for (int j = 0; j < 4; ++j) {
        lo[j] = bf2f((unsigned short)v[j]);
        hi[j] = bf2f((unsigned short)v[4 + j]);
      }
      float* p0 = gdst + ck * 512 + lane * 8;
      __builtin_nontemporal_store(lo, (vf4*)p0);
      __builtin_nontemporal_store(hi, (vf4*)(p0 + 4));
    }
  }
}

// ---------------- K4: classifier head (sums out-partials, writes out + logits) ----------------
__global__ __launch_bounds__(256) void k_head(
    const float* __restrict__ part,
    const float* __restrict__ n1_g, const float* __restrict__ n1_b,
    const float* __restrict__ n2_g, const float* __restrict__ n2_b,
    const float* __restrict__ w1, const float* __restrict__ b1,
    const float* __restrict__ w2, const float* __restrict__ b2,
    float* __restrict__ dout)
{
  int tid = threadIdx.x, lane = tid & 63, w = tid >> 6;
  int b = blockIdx.x;
  __shared__ float h1s[2048];
  __shared__ float red[8];
  float vals[8];
  float s1 = 0.f, s2 = 0.f;
  #pragma unroll
  for (int j = 0; j < 8; ++j) {
    long idx = (long)b * NP + j * 256 + tid;
    float v = part[idx] + part[65536 + idx];
    dout[OUT_OFF + idx] = v;
    vals[j] = v; s1 += v; s2 += v * v;
  }
  #pragma unroll
  for (int m = 32; m; m >>= 1) { s1 += __shfl_xor(s1, m); s2 += __shfl_xor(s2, m); }
  if (lane == 0) { red[w] = s1; red[4 + w] = s2; }
  __syncthreads();
  float S1 = red[0] + red[1] + red[2] + red[3];
  float S2 = red[4] + red[5] + red[6] + red[7];
  float mean = S1 * (1.f / 2048.f);
  float var = S2 * (1.f / 2048.f) - mean * mean;
  float rs = rsqrtf(var + EPS);
  __syncthreads();
  #pragma unroll
  for (int j = 0; j < 8; ++j) {
    int p = j * 256 + tid;
    float h = (vals[j] - mean) * rs * n1_g[p] + n1_b[p];
    h = h >= 0.f ? h : 0.2f * h;
    h1s[p] = h;
  }
  __syncthreads();
  float acc = b1[tid];
  const float* wr = w1 + (long)tid * 2048;
  for (int qq = 0; qq < 2048; qq += 4) {
    float4 wv = *(const float4*)(wr + qq);
    acc += wv.x * h1s[qq] + wv.y * h1s[qq + 1] + wv.z * h1s[qq + 2] + wv.w * h1s[qq + 3];
  }
  float t1 = acc, t2 = acc * acc;
  #pragma unroll
  for (int m = 32; m; m >>= 1) { t1 += __shfl_xor(t1, m); t2 += __shfl_xor(t2, m); }
  if (lane == 0) { red[w] = t1; red[4 + w] = t2; }
  __syncthreads();
  float T1 = red[0] + red[1] + red[2] + red[3];
  float T2 = red[4] + red[5] + red[6] + red[7];
  float m2 = T1 * (1.f / 256.f);
  float v2 = T2 * (1.f / 256.f) - m2 * m2;
  float rs2 = rsqrtf(v2 + EPS);
  float h2 = (acc - m2) * rs2 * n2_g[tid] + n2_b[tid];
  h2 = h2 >= 0.f ? h2 : 0.2f * h2;
  float lg = h2 * w2[tid];
  #pragma unroll
  for (int m = 32; m; m >>= 1) lg += __shfl_xor(lg, m);
  __syncthreads();
  if (lane == 0) red[w] = lg;
  __syncthreads();
  if (tid == 0) dout[b] = red[0] + red[1] + red[2] + red[3] + b2[0];
}

extern "C" void kernel_launch(void* const* d_in, const int* in_sizes, int n_in,
                              void* d_out, int out_size, void* d_ws, size_t ws_size,
                              hipStream_t stream)
{
  const float* img     = (const float*)d_in[0];
  const float* pathway = (const float*)d_in[1];
  const float* qw      = (const float*)d_in[2];
  const float* qw2     = (const float*)d_in[3];
  const float* kw      = (const float*)d_in[4];
  const float* vw      = (const float*)d_in[5];
  const float* vw2     = (const float*)d_in[6];
  const float* q_g     = (const float*)d_in[7];
  const float* q_b     = (const float*)d_in[8];
  const float* k_g     = (const float*)d_in[9];
  const float* k_b     = (const float*)d_in[10];
  const float* v_g     = (const float*)d_in[11];
  const float* v_b     = (const float*)d_in[12];
  const float* n1_g    = (const float*)d_in[13];
  const float* n1_b    = (const float*)d_in[14];
  const float* n2_g    = (const float*)d_in[15];
  const float* n2_b    = (const float*)d_in[16];
  const float* w1      = (const float*)d_in[17];
  const float* b1      = (const float*)d_in[18];
  const float* w2      = (const float*)d_in[19];
  const float* b2      = (const float*)d_in[20];
  float* dout = (float*)d_out;

  // workspace: qm bf16 @0 (8MB); km bf16 @8MB (16MB); vm f32 @24MB (512KB); part f32 @24.5MB (512KB)
  unsigned short* qm_ws   = (unsigned short*)d_ws;
  unsigned short* km_ws   = (unsigned short*)((char*)d_ws + 8388608);
  float*          vm_ws   = (float*)((char*)d_ws + 25165824);
  float*          part_ws = (float*)((char*)d_ws + 25690112);

  k_qm<<<dim3(2048), dim3(256), 0, stream>>>(pathway, qw, qw2, q_g, q_b, qm_ws);
  k_kmvm<<<dim3(32768), dim3(256), 0, stream>>>(img, kw, vw, vw2, k_g, k_b, v_g, v_b, km_ws, vm_ws);
  k_attn<<<dim3(8192), dim3(256), 0, stream>>>(qm_ws, km_ws, vm_ws, part_ws, dout);
  k_head<<<dim3(32), dim3(256), 0, stream>>>(part_ws, n1_g, n1_b, n2_g, n2_b, w1, b1, w2, b2, dout);
}

// Round 9
// 430.971 us; speedup vs baseline: 1.2027x; 1.2027x over previous
//
#include <hip/hip_runtime.h>
#include <hip/hip_bf16.h>

#define EPS 1e-5f
#define INV_VRF 4.4194173824159220e-02f  // 2/sqrt(2048)

#define NB 32
#define NP 2048
#define NI 4096
#define ND 64
#define NL 256

#define ATTN_OFF 32L
#define OUT_OFF  268435488L  // 32 + 32*2048*4096

typedef __attribute__((ext_vector_type(4))) float vf4;
typedef __attribute__((ext_vector_type(8))) short vs8;

__device__ __forceinline__ unsigned short f2bf(float f) {
  unsigned int u = __float_as_uint(f);
  unsigned int r = (u + 0x7FFFu + ((u >> 16) & 1u)) >> 16;
  return (unsigned short)r;
}

// permute k-index d (0..63) into MFMA-fragment element order, so a frag for
// (kk, g) is the contiguous 16B at element [kk*32 + g*8 .. +8).
__device__ __forceinline__ int kperm(int d) {
  int dd = d & 31;
  return (d & 32) + (((dd & 15) >> 2) << 3) + ((dd >> 4) << 2) + (dd & 3);
}

// ---------------- K1: qm = lrelu( lrelu(LN(s*qw)) @ qw2 ), bf16 (permuted cols) ----------------
__global__ __launch_bounds__(256) void k_qm(
    const float* __restrict__ pathway, const float* __restrict__ qw,
    const float* __restrict__ qw2, const float* __restrict__ q_g,
    const float* __restrict__ q_b, unsigned short* __restrict__ qm)
{
  __shared__ float qw2s[64 * 64];
  int tid = threadIdx.x, lane = tid & 63, w = tid >> 6;
  for (int idx = tid; idx < 4096; idx += 256) qw2s[idx] = qw2[idx];
  float qwv = qw[lane], qg = q_g[lane], qb = q_b[lane];
  float s1 = qwv, s2 = qwv * qwv;
  #pragma unroll
  for (int m = 32; m; m >>= 1) { s1 += __shfl_xor(s1, m); s2 += __shfl_xor(s2, m); }
  float mq = s1 * (1.f / 64.f), vq = s2 * (1.f / 64.f) - mq * mq;
  float qc = qwv - mq;
  int pdst = kperm(lane);
  __syncthreads();
  long base = (long)blockIdx.x * 32 + w * 8;
  for (int r = 0; r < 8; ++r) {
    long row = base + r;
    float s = pathway[row];
    float alpha = s * rsqrtf(s * s * vq + EPS);
    float t = alpha * qc * qg + qb;
    t = t >= 0.f ? t : 0.2f * t;
    float acc = 0.f;
    #pragma unroll
    for (int h = 0; h < 64; ++h) acc += __shfl(t, h) * qw2s[h * 64 + lane];
    acc = acc >= 0.f ? acc : 0.2f * acc;
    qm[row * 64 + pdst] = f2bf(acc);
  }
}

// ---------------- K2: km = LN(img_t@kw) bf16 (permuted cols) ; vm = lrelu(LN(img_t@vw))@vw2 ----------------
__global__ __launch_bounds__(256) void k_kmvm(
    const float* __restrict__ img, const float* __restrict__ kw,
    const float* __restrict__ vw, const float* __restrict__ vw2,
    const float* __restrict__ k_g, const float* __restrict__ k_b,
    const float* __restrict__ v_g, const float* __restrict__ v_b,
    unsigned short* __restrict__ km, float* __restrict__ vm)
{
  int tid = threadIdx.x, lane = tid & 63, w = tid >> 6;
  long row = (long)blockIdx.x * 4 + w;      // b*4096 + i
  int b = (int)(row >> 12), i = (int)(row & 4095);
  const float* ib = img + (long)b * 4 * 4096 + i;
  float xv = (lane < 4) ? ib[lane * 4096] : 0.f;
  float x0 = __shfl(xv, 0), x1 = __shfl(xv, 1), x2 = __shfl(xv, 2), x3 = __shfl(xv, 3);
  int d = lane;
  float kp = x0 * kw[d] + x1 * kw[64 + d] + x2 * kw[128 + d] + x3 * kw[192 + d];
  float vp = x0 * vw[d] + x1 * vw[64 + d] + x2 * vw[128 + d] + x3 * vw[192 + d];
  float a1 = kp, a2 = kp * kp, a3 = vp, a4 = vp * vp;
  #pragma unroll
  for (int m = 32; m; m >>= 1) {
    a1 += __shfl_xor(a1, m); a2 += __shfl_xor(a2, m);
    a3 += __shfl_xor(a3, m); a4 += __shfl_xor(a4, m);
  }
  float mk = a1 * (1.f / 64.f), vk = a2 * (1.f / 64.f) - mk * mk;
  float mv = a3 * (1.f / 64.f), vv = a4 * (1.f / 64.f) - mv * mv;
  float kmv = (kp - mk) * rsqrtf(vk + EPS) * k_g[d] + k_b[d];
  km[row * 64 + kperm(d)] = f2bf(kmv);
  float y = (vp - mv) * rsqrtf(vv + EPS) * v_g[d] + v_b[d];
  y = y >= 0.f ? y : 0.2f * y;
  float pv = y * vw2[d];
  #pragma unroll
  for (int m = 32; m; m >>= 1) pv += __shfl_xor(pv, m);
  if (lane == 0) vm[row] = pv;
}

// ---------------- K3: attn = softsign(relu(qm@km^T)/vrf) -> d_out ; out = attn@vm ----------------
// R2 structure + register-double-buffered B-frag prefetch: loads for step s+1 are issued
// BEFORE stores(s), so the per-use vmcnt wait never drains the previous step's NT stores.
#define PREFETCH(SS, B0ARR, B1ARR) do { \
    int i0n = (SS) * 128; \
    _Pragma("unroll") \
    for (int nt = 0; nt < 8; ++nt) { \
      const unsigned short* krow = kb + (long)(i0n + nt * 16 + c) * 64; \
      B0ARR[nt] = *(const vs8*)(krow + g * 8); \
      B1ARR[nt] = *(const vs8*)(krow + 32 + g * 8); \
    } \
  } while (0)

#define KSTEP(SS, B0ARR, B1ARR) do { \
    int i0 = (SS) * 128; \
    vf4 acc[8]; \
    _Pragma("unroll") \
    for (int nt = 0; nt < 8; ++nt) acc[nt] = (vf4){0.f, 0.f, 0.f, 0.f}; \
    _Pragma("unroll") \
    for (int nt = 0; nt < 8; ++nt) { \
      acc[nt] = __builtin_amdgcn_mfma_f32_16x16x32_bf16(afr0, B0ARR[nt], acc[nt], 0, 0, 0); \
      acc[nt] = __builtin_amdgcn_mfma_f32_16x16x32_bf16(afr1, B1ARR[nt], acc[nt], 0, 0, 0); \
    } \
    _Pragma("unroll") \
    for (int nt = 0; nt < 8; ++nt) { \
      _Pragma("unroll") \
      for (int r = 0; r < 4; ++r) { \
        float x = fmaxf(acc[nt][r], 0.f) * INV_VRF; \
        float y = x * __builtin_amdgcn_rcpf(x + 0.5f); \
        int row = g * 4 + r; \
        int f4 = (nt * 4 + (c >> 2)) ^ row; \
        trw[row * 128 + f4 * 4 + (c & 3)] = y; \
      } \
    } \
    _Pragma("unroll") \
    for (int pass = 0; pass < 2; ++pass) { \
      vf4 vmv = *(const vf4*)(vmb + i0 + pass * 64 + c * 4); \
      _Pragma("unroll") \
      for (int j = 0; j < 4; ++j) { \
        int row = j * 4 + g; \
        int f4 = (pass * 16 + c) ^ row; \
        vf4 yv = *(const vf4*)&trw[row * 128 + f4 * 4]; \
        __builtin_nontemporal_store(yv, (vf4*)(outbase + (long)row * NI + i0 + pass * 64 + c * 4)); \
        oacc[j] += yv[0] * vmv[0] + yv[1] * vmv[1] + yv[2] * vmv[2] + yv[3] * vmv[3]; \
      } \
    } \
  } while (0)

__global__ __launch_bounds__(256, 2) void k_attn(
    const unsigned short* __restrict__ qm, const unsigned short* __restrict__ km,
    const float* __restrict__ vm, float* __restrict__ dout)
{
  __shared__ __align__(16) float tr_s[4][16 * 128];  // per-wave 16x128 f32, f4-XOR swizzled
  int tid = threadIdx.x, lane = tid & 63, w = tid >> 6;
  int g = lane >> 4, c = lane & 15;
  // XCD swizzle: blocks sharing b land on one XCD (1024 = 8 xcd * 128)
  int bid = blockIdx.x;
  int lbid = (bid & 7) * 128 + (bid >> 3);
  int b = lbid >> 5, pt = lbid & 31;
  long p_base = (long)b * NP + pt * 64;
  int prow = w * 16;

  // A fragments: rows p_base+prow+c, permuted element order -> one vs8 load per half
  const unsigned short* qrow = qm + (p_base + prow + c) * 64;
  vs8 afr0 = *(const vs8*)(qrow + g * 8);
  vs8 afr1 = *(const vs8*)(qrow + 32 + g * 8);

  const unsigned short* kb = km + (long)b * NI * 64;
  const float* vmb = vm + (long)b * NI;
  float* trw = tr_s[w];
  float* outbase = dout + ATTN_OFF + (p_base + prow) * (long)NI;
  float oacc[4] = {0.f, 0.f, 0.f, 0.f};

  vs8 A0[8], A1[8], B0[8], B1[8];
  PREFETCH(0, A0, A1);
  for (int sp = 0; sp < 16; ++sp) {
    int s0 = sp * 2;
    // even step: prefetch s0+1 BEFORE s0's stores, then compute s0 from A
    PREFETCH(s0 + 1, B0, B1);
    __builtin_amdgcn_sched_barrier(0);
    KSTEP(s0, A0, A1);
    // odd step: prefetch s0+2 BEFORE s0+1's stores, then compute s0+1 from B
    if (sp < 15) { PREFETCH(s0 + 2, A0, A1); }
    __builtin_amdgcn_sched_barrier(0);
    KSTEP(s0 + 1, B0, B1);
  }

  // reduce oacc over the 16 c-lanes within each g-group
  #pragma unroll
  for (int m = 1; m <= 8; m <<= 1) {
    #pragma unroll
    for (int j = 0; j < 4; ++j) oacc[j] += __shfl_xor(oacc[j], m);
  }
  if (c == 0) {
    #pragma unroll
    for (int j = 0; j < 4; ++j)
      dout[OUT_OFF + p_base + prow + j * 4 + g] = oacc[j];
  }
}

// ---------------- K4: classifier head ----------------
__global__ __launch_bounds__(256) void k_head(
    const float* __restrict__ n1_g, const float* __restrict__ n1_b,
    const float* __restrict__ n2_g, const float* __restrict__ n2_b,
    const float* __restrict__ w1, const float* __restrict__ b1,
    const float* __restrict__ w2, const float* __restrict__ b2,
    float* __restrict__ dout)
{
  int tid = threadIdx.x, lane = tid & 63, w = tid >> 6;
  int b = blockIdx.x;
  __shared__ float h1s[2048];
  __shared__ float red[8];
  const float* orow = dout + OUT_OFF + (long)b * NP;
  float vals[8];
  float s1 = 0.f, s2 = 0.f;
  #pragma unroll
  for (int j = 0; j < 8; ++j) {
    float v = orow[j * 256 + tid];
    vals[j] = v; s1 += v; s2 += v * v;
  }
  #pragma unroll
  for (int m = 32; m; m >>= 1) { s1 += __shfl_xor(s1, m); s2 += __shfl_xor(s2, m); }
  if (lane == 0) { red[w] = s1; red[4 + w] = s2; }
  __syncthreads();
  float S1 = red[0] + red[1] + red[2] + red[3];
  float S2 = red[4] + red[5] + red[6] + red[7];
  float mean = S1 * (1.f / 2048.f);
  float var = S2 * (1.f / 2048.f) - mean * mean;
  float rs = rsqrtf(var + EPS);
  __syncthreads();
  #pragma unroll
  for (int j = 0; j < 8; ++j) {
    int p = j * 256 + tid;
    float h = (vals[j] - mean) * rs * n1_g[p] + n1_b[p];
    h = h >= 0.f ? h : 0.2f * h;
    h1s[p] = h;
  }
  __syncthreads();
  float acc = b1[tid];
  const float* wr = w1 + (long)tid * 2048;
  for (int qq = 0; qq < 2048; qq += 4) {
    float4 wv = *(const float4*)(wr + qq);
    acc += wv.x * h1s[qq] + wv.y * h1s[qq + 1] + wv.z * h1s[qq + 2] + wv.w * h1s[qq + 3];
  }
  float t1 = acc, t2 = acc * acc;
  #pragma unroll
  for (int m = 32; m; m >>= 1) { t1 += __shfl_xor(t1, m); t2 += __shfl_xor(t2, m); }
  if (lane == 0) { red[w] = t1; red[4 + w] = t2; }
  __syncthreads();
  float T1 = red[0] + red[1] + red[2] + red[3];
  float T2 = red[4] + red[5] + red[6] + red[7];
  float m2 = T1 * (1.f / 256.f);
  float v2 = T2 * (1.f / 256.f) - m2 * m2;
  float rs2 = rsqrtf(v2 + EPS);
  float h2 = (acc - m2) * rs2 * n2_g[tid] + n2_b[tid];
  h2 = h2 >= 0.f ? h2 : 0.2f * h2;
  float lg = h2 * w2[tid];
  #pragma unroll
  for (int m = 32; m; m >>= 1) lg += __shfl_xor(lg, m);
  __syncthreads();
  if (lane == 0) red[w] = lg;
  __syncthreads();
  if (tid == 0) dout[b] = red[0] + red[1] + red[2] + red[3] + b2[0];
}

extern "C" void kernel_launch(void* const* d_in, const int* in_sizes, int n_in,
                              void* d_out, int out_size, void* d_ws, size_t ws_size,
                              hipStream_t stream)
{
  const float* img     = (const float*)d_in[0];
  const float* pathway = (const float*)d_in[1];
  const float* qw      = (const float*)d_in[2];
  const float* qw2     = (const float*)d_in[3];
  const float* kw      = (const float*)d_in[4];
  const float* vw      = (const float*)d_in[5];
  const float* vw2     = (const float*)d_in[6];
  const float* q_g     = (const float*)d_in[7];
  const float* q_b     = (const float*)d_in[8];
  const float* k_g     = (const float*)d_in[9];
  const float* k_b     = (const float*)d_in[10];
  const float* v_g     = (const float*)d_in[11];
  const float* v_b     = (const float*)d_in[12];
  const float* n1_g    = (const float*)d_in[13];
  const float* n1_b    = (const float*)d_in[14];
  const float* n2_g    = (const float*)d_in[15];
  const float* n2_b    = (const float*)d_in[16];
  const float* w1      = (const float*)d_in[17];
  const float* b1      = (const float*)d_in[18];
  const float* w2      = (const float*)d_in[19];
  const float* b2      = (const float*)d_in[20];
  float* dout = (float*)d_out;

  // workspace layout (bytes): qm bf16 [32*2048*64] @0 ; km bf16 [32*4096*64] @8MB ; vm f32 [32*4096] @24MB
  unsigned short* qm_ws = (unsigned short*)d_ws;
  unsigned short* km_ws = (unsigned short*)((char*)d_ws + 8388608);
  float*          vm_ws = (float*)((char*)d_ws + 25165824);

  k_qm<<<dim3(2048), dim3(256), 0, stream>>>(pathway, qw, qw2, q_g, q_b, qm_ws);
  k_kmvm<<<dim3(32768), dim3(256), 0, stream>>>(img, kw, vw, vw2, k_g, k_b, v_g, v_b, km_ws, vm_ws);
  k_attn<<<dim3(1024), dim3(256), 0, stream>>>(qm_ws, km_ws, vm_ws, dout);
  k_head<<<dim3(32), dim3(256), 0, stream>>>(n1_g, n1_b, n2_g, n2_b, w1, b1, w2, b2, dout);
}